// Round 5
// baseline (257.173 us; speedup 1.0000x reference)
//
#include <hip/hip_runtime.h>
#include <hip/hip_bf16.h>
#include <hip/hip_fp16.h>

// CRF NLL, B=256, T=1024, L=64. Linear-domain recursion with the input-state
// dimension packed into fp16 pairs: per step 32 readlane (hoisted, no SGPR
// hazard) + 32 v_dot2_f32_f16 (fp32 accumulate). V=exp(trans) packed into 32
// pinned half2 VGPRs. Exact pow-2 renorm with the scale exponent taken from the
// PREVIOUS step's butterfly max (off the critical path; growth/step < 2^16 so
// fp16 pack can't overflow). Meet-in-the-middle fwd/bwd + gold wave + combine.

typedef _Float16 h2 __attribute__((ext_vector_type(2)));
#define B2U(x) __builtin_bit_cast(unsigned, x)
#define U2H(x) __builtin_bit_cast(h2, x)
#define L2E 1.44269504088896340736f
#define LN2 0.69314718055994530942f
#define EXPE(p) __builtin_amdgcn_exp2f((p) * L2E)

#define W_ALL(M) M(0) M(1) M(2) M(3) M(4) M(5) M(6) M(7) M(8) M(9) M(10) M(11) \
 M(12) M(13) M(14) M(15) M(16) M(17) M(18) M(19) M(20) M(21) M(22) M(23) M(24) \
 M(25) M(26) M(27) M(28) M(29) M(30) M(31)

#define DECLW(q) unsigned W##q;
#define LOADF(q) W##q = B2U(__builtin_amdgcn_cvt_pkrtz(EXPE(tcol[(2*(q))*66]), EXPE(tcol[(2*(q)+1)*66])));
#define LOADB(q) W##q = B2U(__builtin_amdgcn_cvt_pkrtz(EXPE(trow[2*(q)]), EXPE(trow[2*(q)+1])));
#define PINW(q)  asm volatile("" : "+v"(W##q));

// All 32 broadcasts first (readlane from even lanes), then all 32 dots.
#define RLD(q) int u##q = __builtin_amdgcn_readlane((int)P, 2*(q));
#define RL_ALL W_ALL(RLD)

#if __has_builtin(__builtin_amdgcn_fdot2)
#define DOTQ(q, acc) acc = __builtin_amdgcn_fdot2(U2H((unsigned)u##q), U2H(W##q), acc, false);
#else
#define DOTQ(q, acc) { h2 _u = U2H((unsigned)u##q), _w = U2H(W##q); \
    acc = fmaf((float)_u[0], (float)_w[0], fmaf((float)_u[1], (float)_w[1], acc)); }
#endif
#define DOT_ALL \
    DOTQ(0,s0)  DOTQ(1,s1)  DOTQ(2,s2)  DOTQ(3,s3)  DOTQ(4,s0)  DOTQ(5,s1) \
    DOTQ(6,s2)  DOTQ(7,s3)  DOTQ(8,s0)  DOTQ(9,s1)  DOTQ(10,s2) DOTQ(11,s3) \
    DOTQ(12,s0) DOTQ(13,s1) DOTQ(14,s2) DOTQ(15,s3) DOTQ(16,s0) DOTQ(17,s1) \
    DOTQ(18,s2) DOTQ(19,s3) DOTQ(20,s0) DOTQ(21,s1) DOTQ(22,s2) DOTQ(23,s3) \
    DOTQ(24,s0) DOTQ(25,s1) DOTQ(26,s2) DOTQ(27,s3) DOTQ(28,s0) DOTQ(29,s1) \
    DOTQ(30,s2) DOTQ(31,s3)

#define BMAX(m) \
    m = fmaxf(m, __shfl_xor(m, 1, 64));  m = fmaxf(m, __shfl_xor(m, 2, 64)); \
    m = fmaxf(m, __shfl_xor(m, 4, 64));  m = fmaxf(m, __shfl_xor(m, 8, 64)); \
    m = fmaxf(m, __shfl_xor(m, 16, 64)); m = fmaxf(m, __shfl_xor(m, 32, 64));

#define EXPO_OF(m) ((int)(((unsigned)__builtin_amdgcn_readfirstlane((int)__float_as_uint(m)) >> 23) & 255u) - 127)

#define ROWF(i) pb[(((i) < 0) ? 0 : (((i) > 1023) ? 1023 : (i))) * 64]

// One step. fwd: a' = E .* (V^T x); bwd: a' = V (E .* x); x = a * 2^-k.
#define STEPX(E) { \
    float sc = __uint_as_float((unsigned)(127 - k) << 23); \
    K += k; \
    float x = FWD ? a * sc : (a * sc) * (E); \
    float xo = __shfl_xor(x, 1, 64); \
    unsigned P = B2U(__builtin_amdgcn_cvt_pkrtz(x, xo)); \
    RL_ALL \
    float s0 = 0.f, s1 = 0.f, s2 = 0.f, s3 = 0.f; \
    DOT_ALL \
    float m = x; \
    BMAX(m) \
    k = EXPO_OF(m); \
    float s = (s0 + s1) + (s2 + s3); \
    a = FWD ? s * (E) : s; }

template<bool FWD>
__device__ __forceinline__ void chain(const float* __restrict__ pred,
                                      const float* __restrict__ trans,
                                      int b, int lane, int sl, int h,
                                      float* __restrict__ wsV,
                                      int* __restrict__ wsK)
{
    const float* pb   = pred + (size_t)b * 65536 + lane;
    const float* tcol = trans + lane;        // fwd: V[i][lane]
    const float* trow = trans + lane * 66;   // bwd: V[lane][i]
    (void)tcol; (void)trow;

    W_ALL(DECLW)
    if (FWD) { W_ALL(LOADF) } else { W_ALL(LOADB) }
    W_ALL(PINW)

    float a;
    int   K = 0;
    if (FWD) a = __builtin_amdgcn_exp2f((pb[0] + trans[64 * 66 + lane]) * L2E);
    else     a = __builtin_amdgcn_exp2f(trow[65] * L2E);

    // seed normalizer
    float m0 = a;
    BMAX(m0)
    int k = EXPO_OF(m0);

    const int dir = FWD ? 1 : -1;
    int n = FWD ? h - 1 : sl - h;
    int r = FWD ? 1 : sl - 1;

    float E0 = EXPE(ROWF(r)), E1 = EXPE(ROWF(r + dir)),
          E2 = EXPE(ROWF(r + 2 * dir)), E3 = EXPE(ROWF(r + 3 * dir));
    while (n >= 4) {
        float F0 = ROWF(r + 4 * dir), F1 = ROWF(r + 5 * dir),
              F2 = ROWF(r + 6 * dir), F3 = ROWF(r + 7 * dir);
        STEPX(E0) STEPX(E1) STEPX(E2) STEPX(E3)
        E0 = EXPE(F0); E1 = EXPE(F1); E2 = EXPE(F2); E3 = EXPE(F3);
        r += 4 * dir; n -= 4;
    }
    if (n > 0) { STEPX(E0) --n; }
    if (n > 0) { STEPX(E1) --n; }
    if (n > 0) { STEPX(E2) }

    wsV[b * 64 + lane] = a;
    if (lane == 0) wsK[b] = K;
}

__global__ __launch_bounds__(64) __attribute__((amdgpu_waves_per_eu(1, 1)))
void chain_kernel(const float* __restrict__ pred,
                  const float* __restrict__ trans,
                  const int*   __restrict__ ref,
                  const int*   __restrict__ seqlen,
                  float* __restrict__ wsA, float* __restrict__ wsB,
                  int* __restrict__ wsKf, int* __restrict__ wsKb,
                  float* __restrict__ out)
{
    const int role = blockIdx.x >> 8;
    const int b    = blockIdx.x & 255;
    const int lane = threadIdx.x;
    const int sl   = seqlen[b];
    const int h    = (sl + 1) >> 1;

    if (role == 0) {
        chain<true>(pred, trans, b, lane, sl, h, wsA, wsKf);
    } else if (role == 1) {
        chain<false>(pred, trans, b, lane, sl, h, wsB, wsKb);
    } else {
        // gold-path score
        const int*   rb = ref  + b * 1024;
        const float* pg = pred + (size_t)b * 65536;
        float acc = 0.f;
        for (int t = lane; t <= sl; t += 64) {
            int from = (t == 0) ? 64 : rb[t - 1];
            int cur  = (t < sl) ? rb[t] : 65;
            acc += trans[from * 66 + cur];
            if (t < sl) acc += pg[t * 64 + cur];
        }
        #pragma unroll
        for (int off = 32; off; off >>= 1) acc += __shfl_xor(acc, off, 64);
        if (lane == 0) atomicAdd(out, -acc);
    }
}

__global__ __launch_bounds__(64) void combine_kernel(
    const float* __restrict__ wsA, const float* __restrict__ wsB,
    const int* __restrict__ wsKf, const int* __restrict__ wsKb,
    float* __restrict__ out)
{
    const int b = blockIdx.x, lane = threadIdx.x;
    float z = wsA[b * 64 + lane] * wsB[b * 64 + lane];
    #pragma unroll
    for (int off = 32; off; off >>= 1) z += __shfl_xor(z, off, 64);
    if (lane == 0) {
        float res = LN2 * (__builtin_amdgcn_logf(z) + (float)(wsKf[b] + wsKb[b]));
        atomicAdd(out, res);
    }
}

extern "C" void kernel_launch(void* const* d_in, const int* in_sizes, int n_in,
                              void* d_out, int out_size, void* d_ws, size_t ws_size,
                              hipStream_t stream) {
    const float* pred   = (const float*)d_in[0];
    const float* trans  = (const float*)d_in[1];
    const int*   ref    = (const int*)d_in[2];
    const int*   seqlen = (const int*)d_in[3];
    float* out = (float*)d_out;

    float* wsA  = (float*)d_ws;            // 256*64 f32
    float* wsB  = wsA + 256 * 64;          // 256*64 f32
    int*   wsKf = (int*)(wsB + 256 * 64);  // 256 i32
    int*   wsKb = wsKf + 256;              // 256 i32

    hipMemsetAsync(out, 0, sizeof(float), stream);
    chain_kernel<<<768, 64, 0, stream>>>(pred, trans, ref, seqlen,
                                         wsA, wsB, wsKf, wsKb, out);
    combine_kernel<<<256, 64, 0, stream>>>(wsA, wsB, wsKf, wsKb, out);
}

// Round 6
// 183.104 us; speedup vs baseline: 1.4045x; 1.4045x over previous
//
#include <hip/hip_runtime.h>
#include <hip/hip_bf16.h>
#include <hip/hip_fp16.h>

// CRF NLL, B=256, T=1024, L=64. Linear-domain recursion, input-state dim packed
// into fp16 pairs: per step 32 v_readlane (hoisted in 16-blocks behind
// sched_barriers -> no SGPR-write hazard) + 32 v_dot2_f32_f16 (fp32 acc).
// V=exp(trans) in 32 pinned packed-half2 VGPRs. NO DS/shfl ops in the loop:
// renorm is exact pow-2 with k from v_readfirstlane (bias -5 keeps fp16 pack in
// range), pair-swap for packing via DPP quad_perm. Meet-in-the-middle fwd/bwd
// waves + gold wave + tiny combine kernel.

typedef _Float16 h2 __attribute__((ext_vector_type(2)));
#define B2U(x) __builtin_bit_cast(unsigned, x)
#define U2H(x) __builtin_bit_cast(h2, x)
#define L2E 1.44269504088896340736f
#define LN2 0.69314718055994530942f
#define EXPE(p) __builtin_amdgcn_exp2f((p) * L2E)
#define SBAR __builtin_amdgcn_sched_barrier(0)

#define W_ALL(M) M(0) M(1) M(2) M(3) M(4) M(5) M(6) M(7) M(8) M(9) M(10) M(11) \
 M(12) M(13) M(14) M(15) M(16) M(17) M(18) M(19) M(20) M(21) M(22) M(23) M(24) \
 M(25) M(26) M(27) M(28) M(29) M(30) M(31)

#define DECLW(q) unsigned W##q;
#define LOADF(q) W##q = B2U(__builtin_amdgcn_cvt_pkrtz(EXPE(tcol[(2*(q))*66]), EXPE(tcol[(2*(q)+1)*66])));
#define LOADB(q) W##q = B2U(__builtin_amdgcn_cvt_pkrtz(EXPE(trow[2*(q)]), EXPE(trow[2*(q)+1])));
#define PINW(q)  asm volatile("" : "+v"(W##q));

#define RLD(q) int u##q = __builtin_amdgcn_readlane((int)P, 2*(q));
#define RL16A RLD(0) RLD(1) RLD(2) RLD(3) RLD(4) RLD(5) RLD(6) RLD(7) \
              RLD(8) RLD(9) RLD(10) RLD(11) RLD(12) RLD(13) RLD(14) RLD(15)
#define RL16B RLD(16) RLD(17) RLD(18) RLD(19) RLD(20) RLD(21) RLD(22) RLD(23) \
              RLD(24) RLD(25) RLD(26) RLD(27) RLD(28) RLD(29) RLD(30) RLD(31)

#if __has_builtin(__builtin_amdgcn_fdot2)
#define DOTQ(q, acc) acc = __builtin_amdgcn_fdot2(U2H((unsigned)u##q), U2H(W##q), acc, false);
#else
#define DOTQ(q, acc) { h2 _u = U2H((unsigned)u##q), _w = U2H(W##q); \
    acc = fmaf((float)_u[0], (float)_w[0], fmaf((float)_u[1], (float)_w[1], acc)); }
#endif
#define DOT16A \
    DOTQ(0,s0)  DOTQ(1,s1)  DOTQ(2,s2)  DOTQ(3,s3)  DOTQ(4,s0)  DOTQ(5,s1) \
    DOTQ(6,s2)  DOTQ(7,s3)  DOTQ(8,s0)  DOTQ(9,s1)  DOTQ(10,s2) DOTQ(11,s3) \
    DOTQ(12,s0) DOTQ(13,s1) DOTQ(14,s2) DOTQ(15,s3)
#define DOT16B \
    DOTQ(16,s0) DOTQ(17,s1) DOTQ(18,s2) DOTQ(19,s3) DOTQ(20,s0) DOTQ(21,s1) \
    DOTQ(22,s2) DOTQ(23,s3) DOTQ(24,s0) DOTQ(25,s1) DOTQ(26,s2) DOTQ(27,s3) \
    DOTQ(28,s0) DOTQ(29,s1) DOTQ(30,s2) DOTQ(31,s3)

#define ROWF(i) pb[(((i) < 0) ? 0 : (((i) > 1023) ? 1023 : (i))) * 64]

// quad_perm [1,0,3,2] = swap lane pairs; VALU DPP, no LDS.
#define DPPSWAP(x) __uint_as_float((unsigned)__builtin_amdgcn_mov_dpp( \
    (int)__float_as_uint(x), 0xB1, 0xF, 0xF, true))

// One step. fwd: a' = E .* (V^T x); bwd: a' = V (E .* x); x = a * 2^-k.
// k = (IEEE exponent of lane0's a) + 5   (bias keeps fp16 pack in range; exact)
#define STEPX(E) { \
    unsigned abits = (unsigned)__builtin_amdgcn_readfirstlane((int)__float_as_uint(a)); \
    int k = (int)((abits >> 23) & 255u) - 122; \
    K += k; \
    float sc = __uint_as_float((unsigned)(127 - k) << 23); \
    float x = FWD ? a * sc : (a * sc) * (E); \
    float xo = DPPSWAP(x); \
    unsigned P = B2U(__builtin_amdgcn_cvt_pkrtz(x, xo)); \
    float s0 = 0.f, s1 = 0.f, s2 = 0.f, s3 = 0.f; \
    RL16A \
    SBAR; \
    DOT16A \
    RL16B \
    SBAR; \
    DOT16B \
    float s = (s0 + s1) + (s2 + s3); \
    a = FWD ? s * (E) : s; }

template<bool FWD>
__device__ __forceinline__ void chain(const float* __restrict__ pred,
                                      const float* __restrict__ trans,
                                      int b, int lane, int sl, int h,
                                      float* __restrict__ wsV,
                                      int* __restrict__ wsK)
{
    const float* pb   = pred + (size_t)b * 65536 + lane;
    const float* tcol = trans + lane;        // fwd: V[i][lane]
    const float* trow = trans + lane * 66;   // bwd: V[lane][i]
    (void)tcol; (void)trow;

    W_ALL(DECLW)
    if (FWD) { W_ALL(LOADF) } else { W_ALL(LOADB) }
    W_ALL(PINW)

    float a;
    int   K = 0;
    if (FWD) a = __builtin_amdgcn_exp2f((pb[0] + trans[64 * 66 + lane]) * L2E);
    else     a = __builtin_amdgcn_exp2f(trow[65] * L2E);

    const int dir = FWD ? 1 : -1;
    int n = FWD ? h - 1 : sl - h;
    int r = FWD ? 1 : sl - 1;

    float E0 = EXPE(ROWF(r)), E1 = EXPE(ROWF(r + dir)),
          E2 = EXPE(ROWF(r + 2 * dir)), E3 = EXPE(ROWF(r + 3 * dir));
    while (n >= 4) {
        float F0 = ROWF(r + 4 * dir), F1 = ROWF(r + 5 * dir),
              F2 = ROWF(r + 6 * dir), F3 = ROWF(r + 7 * dir);
        STEPX(E0) STEPX(E1) STEPX(E2) STEPX(E3)
        E0 = EXPE(F0); E1 = EXPE(F1); E2 = EXPE(F2); E3 = EXPE(F3);
        r += 4 * dir; n -= 4;
    }
    if (n > 0) { STEPX(E0) --n; }
    if (n > 0) { STEPX(E1) --n; }
    if (n > 0) { STEPX(E2) }

    wsV[b * 64 + lane] = a;
    if (lane == 0) wsK[b] = K;
}

__global__ __launch_bounds__(64) __attribute__((amdgpu_waves_per_eu(1, 1)))
void chain_kernel(const float* __restrict__ pred,
                  const float* __restrict__ trans,
                  const int*   __restrict__ ref,
                  const int*   __restrict__ seqlen,
                  float* __restrict__ wsA, float* __restrict__ wsB,
                  int* __restrict__ wsKf, int* __restrict__ wsKb,
                  float* __restrict__ out)
{
    const int role = blockIdx.x >> 8;
    const int b    = blockIdx.x & 255;
    const int lane = threadIdx.x;
    const int sl   = seqlen[b];
    const int h    = (sl + 1) >> 1;

    if (role == 0) {
        chain<true>(pred, trans, b, lane, sl, h, wsA, wsKf);
    } else if (role == 1) {
        chain<false>(pred, trans, b, lane, sl, h, wsB, wsKb);
    } else {
        // gold-path score
        const int*   rb = ref  + b * 1024;
        const float* pg = pred + (size_t)b * 65536;
        float acc = 0.f;
        for (int t = lane; t <= sl; t += 64) {
            int from = (t == 0) ? 64 : rb[t - 1];
            int cur  = (t < sl) ? rb[t] : 65;
            acc += trans[from * 66 + cur];
            if (t < sl) acc += pg[t * 64 + cur];
        }
        #pragma unroll
        for (int off = 32; off; off >>= 1) acc += __shfl_xor(acc, off, 64);
        if (lane == 0) atomicAdd(out, -acc);
    }
}

__global__ __launch_bounds__(64) void combine_kernel(
    const float* __restrict__ wsA, const float* __restrict__ wsB,
    const int* __restrict__ wsKf, const int* __restrict__ wsKb,
    float* __restrict__ out)
{
    const int b = blockIdx.x, lane = threadIdx.x;
    float z = wsA[b * 64 + lane] * wsB[b * 64 + lane];
    #pragma unroll
    for (int off = 32; off; off >>= 1) z += __shfl_xor(z, off, 64);
    if (lane == 0) {
        float res = LN2 * (__builtin_amdgcn_logf(z) + (float)(wsKf[b] + wsKb[b]));
        atomicAdd(out, res);
    }
}

extern "C" void kernel_launch(void* const* d_in, const int* in_sizes, int n_in,
                              void* d_out, int out_size, void* d_ws, size_t ws_size,
                              hipStream_t stream) {
    const float* pred   = (const float*)d_in[0];
    const float* trans  = (const float*)d_in[1];
    const int*   ref    = (const int*)d_in[2];
    const int*   seqlen = (const int*)d_in[3];
    float* out = (float*)d_out;

    float* wsA  = (float*)d_ws;            // 256*64 f32
    float* wsB  = wsA + 256 * 64;          // 256*64 f32
    int*   wsKf = (int*)(wsB + 256 * 64);  // 256 i32
    int*   wsKb = wsKf + 256;              // 256 i32

    hipMemsetAsync(out, 0, sizeof(float), stream);
    chain_kernel<<<768, 64, 0, stream>>>(pred, trans, ref, seqlen,
                                         wsA, wsB, wsKf, wsKb, out);
    combine_kernel<<<256, 64, 0, stream>>>(wsA, wsB, wsKf, wsKb, out);
}